// Round 10
// baseline (146.036 us; speedup 1.0000x reference)
//
#include <hip/hip_runtime.h>
#include <cmath>

// GAT layer: N=4096 nodes, FIN=128, F=64 per head, H=8 heads.
//   k0: pack A -> transposed masks bitsT[word][row]; W/X -> MFMA frag order.
//   k1: feats = X @ W[h] f16 MFMA, coalesced fragment streams; factored
//       exps es/esn/et/etn (f16); feats -> MFMA-B-swizzled f16.
//   k2: P = mask * max(es*et, esn*etn) packed f16; denom via MFMA vs ones;
//       PV via mfma 16x16x32. R10: flat-register 2-stage software pipeline
//       (16 named h8 + 8 named uint2), one ct in flight while the previous
//       computes -- attn is latency-exposed (measured ~38us vs ~7.5us TCP
//       floor), and R8 showed struct-based stages go to scratch.

#define NN 4096
#define FIN 128
#define FF 64
#define HH 8

typedef _Float16 h2 __attribute__((ext_vector_type(2)));
typedef _Float16 h4 __attribute__((ext_vector_type(4)));
typedef _Float16 h8 __attribute__((ext_vector_type(8)));
typedef float f32x2 __attribute__((ext_vector_type(2)));
typedef float f32x4 __attribute__((ext_vector_type(4)));

union H8 {
  h8 v;
  h2 p[4];
};
union H4 {
  h4 v;
  h2 p[2];
};

// ---------------------------------------------------------------- kernel 0
__global__ __launch_bounds__(256) void pack_kernel(
    const int* __restrict__ A, const float* __restrict__ W,
    const float* __restrict__ X, unsigned long long* __restrict__ bitsT,
    _Float16* __restrict__ Wsw, _Float16* __restrict__ Xsw) {
  const int b = blockIdx.x;
  const int tid = threadIdx.x;
  const int wave = tid >> 6, lane = tid & 63;
  if (b < NN) {
    __shared__ int ldsT[4][4][256];
    const int* ar = A + (size_t)b * NN;
    int4 v[4];
#pragma unroll
    for (int it = 0; it < 4; ++it) {
      const int g = wave * 4 + it;
      v[it] = *(const int4*)(ar + g * 256 + lane * 4);
    }
#pragma unroll
    for (int it = 0; it < 4; ++it) *(int4*)&ldsT[wave][it][lane * 4] = v[it];
#pragma unroll
    for (int it = 0; it < 4; ++it) {
      const int g = wave * 4 + it;
      int w0 = ldsT[wave][it][0 * 64 + lane];
      int w1 = ldsT[wave][it][1 * 64 + lane];
      int w2 = ldsT[wave][it][2 * 64 + lane];
      int w3 = ldsT[wave][it][3 * 64 + lane];
      unsigned long long m0 = __ballot(w0 != 0);
      unsigned long long m1 = __ballot(w1 != 0);
      unsigned long long m2 = __ballot(w2 != 0);
      unsigned long long m3 = __ballot(w3 != 0);
      if (lane == 0) {
        bitsT[(size_t)(g * 4 + 0) * NN + b] = m0;
        bitsT[(size_t)(g * 4 + 1) * NN + b] = m1;
        bitsT[(size_t)(g * 4 + 2) * NN + b] = m2;
        bitsT[(size_t)(g * 4 + 3) * NN + b] = m3;
      }
    }
  } else if (b < NN + 2) {
    const int h0 = (b - NN) * 4;
    for (int h = h0; h < h0 + 4; ++h) {
      for (int c = tid; c < 1024; c += 256) {  // (kt, nb, lane)
        int ln = c & 63, nb = (c >> 6) & 3, kt = c >> 8;
        int f = nb * 16 + (ln & 15);
        int k0 = kt * 32 + (ln >> 4) * 8;
        h8 v;
#pragma unroll
        for (int j = 0; j < 8; ++j)
          v[j] = (_Float16)W[((size_t)(h * FIN) + k0 + j) * FF + f];
        *(h8*)(Wsw + ((size_t)(((h * 4 + kt) * 4 + nb) * 64 + ln)) * 8) = v;
      }
    }
  } else {
    const int tile = (b - NN - 2) * 4 + wave;  // 16-row tile, 0..255
    const int l16 = lane & 15, quad = lane >> 4;
    const float* xr = X + (size_t)(tile * 16 + l16) * FIN;
#pragma unroll
    for (int kt = 0; kt < 4; ++kt) {
      int k0 = kt * 32 + quad * 8;
      f32x4 x0 = *(const f32x4*)(xr + k0);
      f32x4 x1 = *(const f32x4*)(xr + k0 + 4);
      h8 v = {(_Float16)x0[0], (_Float16)x0[1], (_Float16)x0[2],
              (_Float16)x0[3], (_Float16)x1[0], (_Float16)x1[1],
              (_Float16)x1[2], (_Float16)x1[3]};
      *(h8*)(Xsw + ((size_t)((tile * 4 + kt) * 64 + lane)) * 8) = v;
    }
  }
}

// ---------------------------------------------------------------- kernel 1
__global__ __launch_bounds__(256) void feats_kernel(
    const _Float16* __restrict__ Xsw, const _Float16* __restrict__ Wsw,
    const float* __restrict__ a_self, const float* __restrict__ a_neigh,
    _Float16* __restrict__ feats_sw, _Float16* __restrict__ es_h,
    _Float16* __restrict__ esn_h, _Float16* __restrict__ et_h,
    _Float16* __restrict__ etn_h) {
  const int h = blockIdx.y;
  const int tid = threadIdx.x, wave = tid >> 6, lane = tid & 63;
  const int l16 = lane & 15, quad = lane >> 4;
  const int rt = blockIdx.x * 4 + wave;  // 16-row tile
  const int r0 = rt * 16;

  f32x4 acc[4];
#pragma unroll
  for (int nb = 0; nb < 4; ++nb) acc[nb] = (f32x4){0.f, 0.f, 0.f, 0.f};

  const _Float16* xp = Xsw + ((size_t)(rt * 4) * 64 + lane) * 8;
  const _Float16* wp = Wsw + ((size_t)(h * 16) * 64 + lane) * 8;
  h8 Af[4];
#pragma unroll
  for (int kt = 0; kt < 4; ++kt) Af[kt] = *(const h8*)(xp + kt * 512);
#pragma unroll
  for (int kt = 0; kt < 4; ++kt)
#pragma unroll
    for (int nb = 0; nb < 4; ++nb) {
      h8 Bf = *(const h8*)(wp + (kt * 4 + nb) * 512);
      acc[nb] = __builtin_amdgcn_mfma_f32_16x16x32_f16(Af[kt], Bf, acc[nb], 0, 0, 0);
    }

  float as[4], an[4];
#pragma unroll
  for (int nb = 0; nb < 4; ++nb) {
    as[nb] = a_self[h * FF + nb * 16 + l16];
    an[nb] = a_neigh[h * FF + nb * 16 + l16];
  }
#pragma unroll
  for (int r = 0; r < 4; ++r) {
    float ps = acc[0][r] * as[0] + acc[1][r] * as[1] + acc[2][r] * as[2] +
               acc[3][r] * as[3];
    float pn = acc[0][r] * an[0] + acc[1][r] * an[1] + acc[2][r] * an[2] +
               acc[3][r] * an[3];
#pragma unroll
    for (int m = 1; m <= 8; m <<= 1) {
      ps += __shfl_xor(ps, m, 64);
      pn += __shfl_xor(pn, m, 64);
    }
    if (l16 == 0) {
      int node = h * NN + r0 + quad * 4 + r;
      es_h[node] = (_Float16)__expf(ps - 2.0f);
      esn_h[node] = (_Float16)__expf(0.2f * ps - 2.0f);
      et_h[node] = (_Float16)__expf(pn - 2.0f);
      etn_h[node] = (_Float16)__expf(0.2f * pn - 2.0f);
    }
  }

  const int kb = r0 >> 5;
  const int quadA = ((r0 >> 4) & 1) * 2 + (quad >> 1);
  const int jbase = (quad & 1) << 2;
#pragma unroll
  for (int nb = 0; nb < 4; ++nb) {
    h4 v = {(_Float16)acc[nb][0], (_Float16)acc[nb][1], (_Float16)acc[nb][2],
            (_Float16)acc[nb][3]};
    size_t off = ((size_t)((h * 128 + kb) * 4 + nb) << 9) +
                 ((quadA * 16 + l16) << 3) + jbase;
    *(h4*)(feats_sw + off) = v;
  }
}

// ---------------------------------------------------------------- kernel 2
// grid 512 = rb*8 + h; 64-row blocks; 4 waves x 16 cts; rg=4 row-frags.
// Flat-register two-stage pipeline: stage Y's loads issue before stage X's
// compute body, so every global load has a full ct of latency slack.

#define LOADSET(p0, p1, p2, p3, p4, p5, p6, p7, q0, q1, q2, q3, CT)          \
  {                                                                          \
    const _Float16* fk_ = fb + ((size_t)(CT) << 12);                         \
    p0 = *(const h8*)(fk_);                                                  \
    p1 = *(const h8*)(fk_ + 512);                                            \
    p2 = *(const h8*)(fk_ + 1024);                                           \
    p3 = *(const h8*)(fk_ + 1536);                                           \
    p4 = *(const h8*)(fk_ + 2048);                                           \
    p5 = *(const h8*)(fk_ + 2560);                                           \
    p6 = *(const h8*)(fk_ + 3072);                                           \
    p7 = *(const h8*)(fk_ + 3584);                                           \
    const unsigned long long* bp_ = btb + (size_t)(CT) * NN;                 \
    q0 = *(const uint2*)(bp_);                                               \
    q1 = *(const uint2*)(bp_ + 16);                                          \
    q2 = *(const uint2*)(bp_ + 32);                                          \
    q3 = *(const uint2*)(bp_ + 48);                                          \
  }

#define KFBODY(ET_, ETN_, B0_, B1_, B2_, B3_, w0_, w1_, w2_, w3_)            \
  {                                                                          \
    const unsigned ww_[4] = {w0_, w1_, w2_, w3_};                            \
    _Pragma("unroll") for (int rg = 0; rg < 4; ++rg) {                       \
      unsigned byt_ = (ww_[rg] >> (quad << 3)) & 0xFFu;                      \
      H4 mlo_, mhi_;                                                         \
      mlo_.v = lut16[byt_ & 15u];                                            \
      mhi_.v = lut16[byt_ >> 4];                                             \
      H8 P_;                                                                 \
      _Pragma("unroll") for (int p = 0; p < 4; ++p) {                        \
        h2 a_ = esp[rg] * ET_.p[p];                                          \
        h2 b_ = esnp[rg] * ETN_.p[p];                                        \
        h2 r_ = __builtin_elementwise_max(a_, b_);                           \
        P_.p[p] = r_ * (p < 2 ? mlo_.p[p] : mhi_.p[p - 2]);                  \
      }                                                                      \
      acc[rg][0] =                                                           \
          __builtin_amdgcn_mfma_f32_16x16x32_f16(P_.v, B0_, acc[rg][0], 0, 0, 0); \
      acc[rg][1] =                                                           \
          __builtin_amdgcn_mfma_f32_16x16x32_f16(P_.v, B1_, acc[rg][1], 0, 0, 0); \
      acc[rg][2] =                                                           \
          __builtin_amdgcn_mfma_f32_16x16x32_f16(P_.v, B2_, acc[rg][2], 0, 0, 0); \
      acc[rg][3] =                                                           \
          __builtin_amdgcn_mfma_f32_16x16x32_f16(P_.v, B3_, acc[rg][3], 0, 0, 0); \
      accd[rg] =                                                             \
          __builtin_amdgcn_mfma_f32_16x16x32_f16(P_.v, onesB, accd[rg], 0, 0, 0); \
    }                                                                        \
  }

#define COMPUTE(p0, p1, p2, p3, p4, p5, p6, p7, q0, q1, q2, q3, CT)          \
  {                                                                          \
    const int ct_ = (CT);                                                    \
    H8 ET0_, ETN0_, ET1_, ETN1_;                                             \
    ET0_.v = *(const h8*)(etp + (ct_ << 6));                                 \
    ETN0_.v = *(const h8*)(etnp + (ct_ << 6));                               \
    ET1_.v = *(const h8*)(etp + (ct_ << 6) + 32);                            \
    ETN1_.v = *(const h8*)(etnp + (ct_ << 6) + 32);                          \
    KFBODY(ET0_, ETN0_, p0, p1, p2, p3, q0.x, q1.x, q2.x, q3.x)              \
    KFBODY(ET1_, ETN1_, p4, p5, p6, p7, q0.y, q1.y, q2.y, q3.y)              \
  }

__global__ __launch_bounds__(256, 2) void attn_kernel(
    const unsigned long long* __restrict__ bitsT,
    const _Float16* __restrict__ feats_sw, const _Float16* __restrict__ es_h,
    const _Float16* __restrict__ esn_h, const _Float16* __restrict__ et_h,
    const _Float16* __restrict__ etn_h, const float* __restrict__ bias,
    float* __restrict__ out) {
  const int bid = blockIdx.x;
  const int h = bid & 7, n0 = (bid >> 3) << 6;  // 64-row tile
  const int tid = threadIdx.x, wave = tid >> 6, lane = tid & 63;
  const int l16 = lane & 15, quad = lane >> 4;

  __shared__ h4 lut16[16];           // 16 x 8B = exactly 32 banks
  __shared__ float accL[4][16][66];  // 16.9 KB (phase-sized)
  __shared__ float denL[4][64];
  if (tid < 16) {
    h4 m;
#pragma unroll
    for (int j = 0; j < 4; ++j) m[j] = (_Float16)((tid >> j) & 1);
    lut16[tid] = m;
  }
  __syncthreads();

  h2 esp[4], esnp[4];
#pragma unroll
  for (int rg = 0; rg < 4; ++rg) {
    _Float16 e = es_h[h * NN + n0 + rg * 16 + l16];
    _Float16 en = esn_h[h * NN + n0 + rg * 16 + l16];
    esp[rg] = (h2){e, e};
    esnp[rg] = (h2){en, en};
  }

  f32x4 acc[4][4];
  f32x4 accd[4];
#pragma unroll
  for (int rg = 0; rg < 4; ++rg) {
    accd[rg] = (f32x4){0.f, 0.f, 0.f, 0.f};
#pragma unroll
    for (int nb = 0; nb < 4; ++nb) acc[rg][nb] = (f32x4){0.f, 0.f, 0.f, 0.f};
  }
  const h8 onesB = {(_Float16)1.f, (_Float16)1.f, (_Float16)1.f,
                    (_Float16)1.f, (_Float16)1.f, (_Float16)1.f,
                    (_Float16)1.f, (_Float16)1.f};

  const unsigned long long* btb = bitsT + n0 + l16;
  const _Float16* etp = et_h + h * NN + (quad << 3);
  const _Float16* etnp = etn_h + h * NN + (quad << 3);
  const _Float16* fb = feats_sw + ((size_t)h << 18) + (lane << 3);

  // two flat register stages
  h8 xa0, xa1, xa2, xa3, xa4, xa5, xa6, xa7;
  h8 xb0, xb1, xb2, xb3, xb4, xb5, xb6, xb7;
  uint2 qa0, qa1, qa2, qa3, qb0, qb1, qb2, qb3;

  LOADSET(xa0, xa1, xa2, xa3, xa4, xa5, xa6, xa7, qa0, qa1, qa2, qa3, wave)
#pragma unroll 1
  for (int i = 0; i < 8; ++i) {
    const int cta = wave + i * 8;
    LOADSET(xb0, xb1, xb2, xb3, xb4, xb5, xb6, xb7, qb0, qb1, qb2, qb3,
            cta + 4)
    COMPUTE(xa0, xa1, xa2, xa3, xa4, xa5, xa6, xa7, qa0, qa1, qa2, qa3, cta)
    if (i < 7) {
      LOADSET(xa0, xa1, xa2, xa3, xa4, xa5, xa6, xa7, qa0, qa1, qa2, qa3,
              cta + 8)
    }
    COMPUTE(xb0, xb1, xb2, xb3, xb4, xb5, xb6, xb7, qb0, qb1, qb2, qb3,
            cta + 4)
  }

  // denominator partials (col-uniform in accd)
  if (l16 == 0) {
#pragma unroll
    for (int rg = 0; rg < 4; ++rg)
#pragma unroll
      for (int r = 0; r < 4; ++r)
        denL[wave][rg * 16 + quad * 4 + r] = accd[rg][r];
  }

  // 4-phase epilogue: 16 rows per phase, 4-way cross-wave reduce
  const int erow = tid >> 4, ec0 = (tid & 15) << 2;
#pragma unroll
  for (int ph = 0; ph < 4; ++ph) {
    __syncthreads();
#pragma unroll
    for (int nb = 0; nb < 4; ++nb)
#pragma unroll
      for (int r = 0; r < 4; ++r)
        accL[wave][quad * 4 + r][nb * 16 + l16] = acc[ph][nb][r];
    __syncthreads();
    const int grow = ph * 16 + erow;
    float dn = denL[0][grow] + denL[1][grow] + denL[2][grow] + denL[3][grow];
    float inv = 1.0f / dn;  // self loop -> dn > 0
    f32x2 v0 = (f32x2){0.f, 0.f}, v1 = (f32x2){0.f, 0.f};
#pragma unroll
    for (int w = 0; w < 4; ++w) {
      v0 += *(const f32x2*)&accL[w][erow][ec0];
      v1 += *(const f32x2*)&accL[w][erow][ec0 + 2];
    }
    const f32x4 bv = *(const f32x4*)(bias + h * FF + ec0);
    f32x4 v = {v0[0], v0[1], v1[0], v1[1]};
#pragma unroll
    for (int i = 0; i < 4; ++i) {
      float x = v[i] * inv + bv[i];
      v[i] = x > 0.f ? x : (__expf(x) - 1.0f);
    }
    *(f32x4*)(out + (size_t)(n0 + grow) * (HH * FF) + h * FF + ec0) = v;
  }
}

// ---------------------------------------------------------------- launch
extern "C" void kernel_launch(void* const* d_in, const int* in_sizes, int n_in,
                              void* d_out, int out_size, void* d_ws,
                              size_t ws_size, hipStream_t stream) {
  const float* X = (const float*)d_in[0];
  const int* A = (const int*)d_in[1];
  const float* W = (const float*)d_in[2];
  const float* b = (const float*)d_in[3];
  const float* a_self = (const float*)d_in[4];
  const float* a_neigh = (const float*)d_in[5];
  float* out = (float*)d_out;

  char* ws = (char*)d_ws;
  unsigned long long* bitsT = (unsigned long long*)ws;        // 2 MB
  _Float16* feats_sw = (_Float16*)(ws + (2u << 20));          // 4 MB
  _Float16* es_h = (_Float16*)(ws + (6u << 20));              // 64 KB each
  _Float16* esn_h = (_Float16*)(ws + (6u << 20) + (64u << 10));
  _Float16* et_h = (_Float16*)(ws + (6u << 20) + (128u << 10));
  _Float16* etn_h = (_Float16*)(ws + (6u << 20) + (192u << 10));
  _Float16* Wsw = (_Float16*)(ws + (6u << 20) + (256u << 10));   // 128 KB
  _Float16* Xsw = (_Float16*)(ws + (6u << 20) + (384u << 10));   // 1 MB

  pack_kernel<<<NN + 66, 256, 0, stream>>>(A, W, X, bitsT, Wsw, Xsw);
  feats_kernel<<<dim3(64, 8), 256, 0, stream>>>(Xsw, Wsw, a_self, a_neigh,
                                                feats_sw, es_h, esn_h, et_h,
                                                etn_h);
  attn_kernel<<<512, 256, 0, stream>>>(bitsT, feats_sw, es_h, esn_h, et_h,
                                       etn_h, b, out);
}